// Round 5
// baseline (488.481 us; speedup 1.0000x reference)
//
#include <hip/hip_runtime.h>

typedef __bf16 bf16;
typedef __bf16 bf16x8 __attribute__((ext_vector_type(8)));
typedef float f32x4 __attribute__((ext_vector_type(4)));
typedef float f32x16 __attribute__((ext_vector_type(16)));

// async global->LDS, 16B per lane; LDS dest is wave-uniform base + lane*16
__device__ __forceinline__ void gl_lds16(const bf16* g, bf16* l) {
  __builtin_amdgcn_global_load_lds(
      (__attribute__((address_space(1))) void*)g,
      (__attribute__((address_space(3))) void*)l, 16, 0, 0);
}

// ---------------- fp32 -> bf16 convert, 8 elems/thread ----------------
__global__ __launch_bounds__(256) void cvt_f32_bf16(
    const float* __restrict__ src, bf16* __restrict__ dst, int n8) {
  int i = blockIdx.x * 256 + threadIdx.x;
  if (i >= n8) return;
  const float4* s4 = (const float4*)src;
  float4 a = s4[2 * i], b = s4[2 * i + 1];
  bf16x8 o = {(bf16)a.x, (bf16)a.y, (bf16)a.z, (bf16)a.w,
              (bf16)b.x, (bf16)b.y, (bf16)b.z, (bf16)b.w};
  *(bf16x8*)(dst + (size_t)i * 8) = o;
}

// ------- V [2048,1024] f32 -> VT [1024,2048] bf16, per batch ----------
__global__ __launch_bounds__(256) void transpose_v(
    const float* __restrict__ V, bf16* __restrict__ VT) {
  int b = blockIdx.z;
  const float* Vb = V + (size_t)b * 2048 * 1024;
  bf16* Tb = VT + (size_t)b * 1024 * 2048;
  __shared__ float tile[32][33];  // +1 pad: conflict-free transposed read
  int tx = threadIdx.x, ty = threadIdx.y;
  int x = blockIdx.x * 32 + tx;
  int yb = blockIdx.y * 32;
#pragma unroll
  for (int j = 0; j < 4; j++)
    tile[ty + j * 8][tx] = Vb[(size_t)(yb + ty + j * 8) * 1024 + x];
  __syncthreads();
  int xo = yb + tx;
#pragma unroll
  for (int j = 0; j < 4; j++)
    Tb[(size_t)(blockIdx.x * 32 + ty + j * 8) * 2048 + xo] =
        (bf16)tile[tx][ty + j * 8];
}

// ============== 256x256 double-buffered pipelined MFMA GEMM ===========
// C = A[M,K] * Bm[N,K]^T, bf16 in, 32x32x16 MFMA.
// 512 thr = 8 waves (2M x 4N), 128x64 per wave, acc[4][2] f32x16.
// LDS: 2 buffers of BK=64 K-tiles (128KB) -> 1 block/CU.
// R4 findings: FETCH fixed (49MB, batch-partition ZMAP); bank-conflict
//   counter = intrinsic 4cy/b128 (m134), not addressable. Wall = 2-phase
//   read-burst/MFMA-burst serialization (m233): period 6375cy vs 2065
//   MFMA floor, MfmaUtil 34% == floor/period exactly.
// R5 change: software-pipelined compute_tile. All B-frags (8) + A m-block
//   0 (4) read up-front into named regs; per m-block: issue next block's
//   4 ds_reads, then its 8-MFMA cluster. Compiler's counted lgkmcnt hides
//   reads under ~516cy of MFMA per block. ~215 VGPR (<256 @ 2 waves/EU).
// Schedule (T3+T4): issue tile t+1's 8 gl_lds, THEN vmcnt(8) (tile t
//   landed, t+1 in flight across barriers). Never vmcnt(0) mid-loop.
// MODE 0: C bf16 = acc + bias[col]            (projection)
// MODE 1: C bf16 = mask[col] ? acc/32 : -1e9  (QK^T scores)
// MODE 2: C f32  = acc                        (PV output)
template <int MODE, int ZMAP>
__global__ __launch_bounds__(512, 2) void gemm256(
    const bf16* __restrict__ A, const bf16* __restrict__ Bm,
    void* __restrict__ Cv, const float* __restrict__ bias,
    const int* __restrict__ mask, int M, int N, int K,
    long long sA, long long sB, long long sC) {
  int b, m0, n0;
  if constexpr (ZMAP == 1) {
    // batch-partitioned: XCD c owns batch c entirely (zero cross-XCD share)
    const int L = (blockIdx.z * gridDim.y + blockIdx.y) * gridDim.x +
                  blockIdx.x;
    b = L & 7;
    const int J = L >> 3;                 // tile within batch
    m0 = (J / gridDim.x) * 256;
    n0 = (J % gridDim.x) * 256;
  } else {
    // single-plane rect scheme (proven): per-XCD 8m x 4n block cluster
    b = blockIdx.z;
    const int nx = gridDim.x, nwg = nx * gridDim.y;
    const int orig = blockIdx.y * nx + blockIdx.x;
    const int swz = (orig & 7) * (nwg >> 3) + (orig >> 3);
    m0 = (swz / nx) * 256;
    n0 = (swz % nx) * 256;
  }
  const bf16* Ab = A + (long long)b * sA;
  const bf16* Bb = Bm + (long long)b * sB;

  __shared__ __align__(16) bf16 lds[2][2][256 * 64];  // [buf][A/B][r*64+k]

  const int tid = threadIdx.x, w = tid >> 6, lane = tid & 63;
  const int wr = w >> 2, wc = w & 3;  // wave grid 2x4
  const int fr = lane & 31;           // frag row within 32-tile
  const int fh = lane >> 5;           // k-granule half selector
  // read-side swizzle key: row bits 0-2 XOR (row bits 3-4)<<1
  const int key = (fr & 7) ^ (((fr >> 3) & 3) << 1);
  const bf16* Aq = Ab + (long long)m0 * K;
  const bf16* Bq = Bb + (long long)n0 * K;

  f32x16 acc[4][2];
#pragma unroll
  for (int i = 0; i < 4; i++)
#pragma unroll
    for (int j = 0; j < 2; j++)
#pragma unroll
      for (int r = 0; r < 16; r++) acc[i][j][r] = 0.f;

  // ---- stage K-tile t: 8 gl_lds/thread (A 4 parts + B 4 parts) ----
  // part p covers rows [p*64, p*64+64); wave w owns 8 rows = 1KB/instr.
  // dest row = p*64 + w*8 + srow: row&7 = srow, (row>>3)&3 = w&3.
  const int srow = lane >> 3;  // row within wave's 8
  const int sgsw = (((lane & 7) ^ srow ^ ((w & 3) << 1)) * 8);
  auto stage_tile = [&](int t) {
    const int buf = t & 1;
    const long long gc = (long long)t * 64 + sgsw;
    const int r0 = w * 8 + srow;
#pragma unroll
    for (int p = 0; p < 4; p++) {
      const long long r = p * 64 + r0;
      const int dbase = (p * 64 + w * 8) * 64;  // wave-uniform, linear
      gl_lds16(Aq + r * K + gc, &lds[buf][0][dbase]);
      gl_lds16(Bq + r * K + gc, &lds[buf][1][dbase]);
    }
  };

  // ---- compute one BK=64 tile, software-pipelined over m-blocks ----
  // reads: bfr[2][4] (8) + af[.][4] rotating (4/m-block, issued one
  // block ahead); MFMA cluster (8) per m-block consumes previous reads.
  auto compute_tile = [&](int buf) {
    const bf16* la = &lds[buf][0][0];
    const bf16* lb = &lds[buf][1][0];
    int slot[4];
#pragma unroll
    for (int kk = 0; kk < 4; kk++) slot[kk] = ((kk * 2 + fh) ^ key) * 8;
    bf16x8 bfr[2][4];
#pragma unroll
    for (int ni = 0; ni < 2; ni++)
#pragma unroll
      for (int kk = 0; kk < 4; kk++)
        bfr[ni][kk] =
            *(const bf16x8*)&lb[(wc * 64 + ni * 32 + fr) * 64 + slot[kk]];
    bf16x8 af[2][4];  // rotating 2-deep A pipeline, indices compile-time
#pragma unroll
    for (int kk = 0; kk < 4; kk++)
      af[0][kk] = *(const bf16x8*)&la[(wr * 128 + fr) * 64 + slot[kk]];
#pragma unroll
    for (int mi = 0; mi < 4; mi++) {
      if (mi < 3) {
#pragma unroll
        for (int kk = 0; kk < 4; kk++)
          af[(mi + 1) & 1][kk] =
              *(const bf16x8*)&la[(wr * 128 + (mi + 1) * 32 + fr) * 64 +
                                  slot[kk]];
      }
      __builtin_amdgcn_s_setprio(1);
#pragma unroll
      for (int kk = 0; kk < 4; kk++)
#pragma unroll
        for (int ni = 0; ni < 2; ni++)
          acc[mi][ni] = __builtin_amdgcn_mfma_f32_32x32x16_bf16(
              af[mi & 1][kk], bfr[ni][kk], acc[mi][ni], 0, 0, 0);
      __builtin_amdgcn_s_setprio(0);
    }
  };

  const int NT = K >> 6;  // BK=64 tiles
  stage_tile(0);
  for (int t = 0; t < NT; ++t) {
    if (t + 1 < NT) {
      stage_tile(t + 1);  // issue BEFORE waiting on tile t: stays in flight
      asm volatile("s_waitcnt vmcnt(8)" ::: "memory");  // tile t landed
    } else {
      asm volatile("s_waitcnt vmcnt(0)" ::: "memory");
    }
    __builtin_amdgcn_s_barrier();  // all waves' tile-t stores visible
    compute_tile(t & 1);
    __builtin_amdgcn_s_barrier();  // all waves done reading buf t&1
  }

  // C/D layout (m74/m101-verified): col=lane&31,
  // row = (reg&3) + 8*(reg>>2) + 4*(lane>>5)
  const int ecol = lane & 31, er4 = (lane >> 5) * 4;
  if constexpr (MODE == 0) {
    bf16* C = (bf16*)Cv;
#pragma unroll
    for (int ni = 0; ni < 2; ni++) {
      int col = n0 + wc * 64 + ni * 32 + ecol;
      float bv = bias[col];
#pragma unroll
      for (int mi = 0; mi < 4; mi++)
#pragma unroll
        for (int r = 0; r < 16; r++) {
          int row = m0 + wr * 128 + mi * 32 + er4 + (r & 3) + 8 * (r >> 2);
          C[(long long)row * N + col] = (bf16)(acc[mi][ni][r] + bv);
        }
    }
  } else if constexpr (MODE == 1) {
    bf16* C = (bf16*)Cv + (long long)b * sC;
    const int* mb = mask + b * 2048;
#pragma unroll
    for (int ni = 0; ni < 2; ni++) {
      int col = n0 + wc * 64 + ni * 32 + ecol;
      bool keep = mb[col] != 0;
#pragma unroll
      for (int mi = 0; mi < 4; mi++)
#pragma unroll
        for (int r = 0; r < 16; r++) {
          int row = m0 + wr * 128 + mi * 32 + er4 + (r & 3) + 8 * (r >> 2);
          C[(long long)row * N + col] =
              keep ? (bf16)(acc[mi][ni][r] * 0.03125f) : (bf16)(-1e9f);
        }
    }
  } else {
    float* C = (float*)Cv + (long long)b * sC;
#pragma unroll
    for (int ni = 0; ni < 2; ni++) {
      int col = n0 + wc * 64 + ni * 32 + ecol;
#pragma unroll
      for (int mi = 0; mi < 4; mi++)
#pragma unroll
        for (int r = 0; r < 16; r++) {
          int row = m0 + wr * 128 + mi * 32 + er4 + (r & 3) + 8 * (r >> 2);
          C[(long long)row * N + col] = acc[mi][ni][r];
        }
    }
  }
}

// ------------- row softmax: S bf16 [.,2048] -> P bf16 -----------------
__global__ __launch_bounds__(256) void softmax_rows(
    const bf16* __restrict__ S, bf16* __restrict__ P) {
  long long row = blockIdx.x;
  const bf16x8* src = (const bf16x8*)(S + row * 2048);
  int tid = threadIdx.x, w = tid >> 6, lane = tid & 63;
  bf16x8 v = src[tid];
  float f[8];
#pragma unroll
  for (int i = 0; i < 8; i++) f[i] = (float)v[i];
  float m = f[0];
#pragma unroll
  for (int i = 1; i < 8; i++) m = fmaxf(m, f[i]);
#pragma unroll
  for (int off = 32; off; off >>= 1) m = fmaxf(m, __shfl_xor(m, off, 64));
  __shared__ float redm[4], reds[4];
  if (lane == 0) redm[w] = m;
  __syncthreads();
  m = fmaxf(fmaxf(redm[0], redm[1]), fmaxf(redm[2], redm[3]));
  float e[8], s = 0.f;
#pragma unroll
  for (int i = 0; i < 8; i++) {
    e[i] = __expf(f[i] - m);
    s += e[i];
  }
#pragma unroll
  for (int off = 32; off; off >>= 1) s += __shfl_xor(s, off, 64);
  if (lane == 0) reds[w] = s;
  __syncthreads();
  s = reds[0] + reds[1] + reds[2] + reds[3];
  float inv = 1.0f / s;
  bf16x8 o;
#pragma unroll
  for (int i = 0; i < 8; i++) o[i] = (bf16)(e[i] * inv);
  *(bf16x8*)(P + row * 2048 + tid * 8) = o;
}

extern "C" void kernel_launch(void* const* d_in, const int* in_sizes, int n_in,
                              void* d_out, int out_size, void* d_ws,
                              size_t ws_size, hipStream_t stream) {
  const float* query = (const float*)d_in[0];
  const float* key_in = (const float*)d_in[1];
  const float* value = (const float*)d_in[2];
  const int* mask = (const int*)d_in[3];
  const float* Wq_w = (const float*)d_in[4];
  const float* Wq_b = (const float*)d_in[5];
  const float* Wk_w = (const float*)d_in[6];
  const float* Wk_b = (const float*)d_in[7];
  float* out = (float*)d_out;

  // workspace layout (224 MB), regions time-shared:
  //  [0,128MB):  qx(32) kx(32) wq(2) wk(2)  -> then S bf16 (64)
  //  [128,192MB): qp(32) kp(32)             -> then P bf16 (64)
  //  [192,224MB): vt bf16 (32)
  const size_t MB = 1ull << 20;
  char* base = (char*)d_ws;
  bf16* qx = (bf16*)(base + 0 * MB);
  bf16* kx = (bf16*)(base + 32 * MB);
  bf16* wq = (bf16*)(base + 64 * MB);
  bf16* wk = (bf16*)(base + 66 * MB);
  bf16* S = (bf16*)(base + 0 * MB);
  bf16* qp = (bf16*)(base + 128 * MB);
  bf16* kp = (bf16*)(base + 160 * MB);
  bf16* P = (bf16*)(base + 128 * MB);
  bf16* vt = (bf16*)(base + 192 * MB);

  cvt_f32_bf16<<<8192, 256, 0, stream>>>(query, qx, 2097152);
  cvt_f32_bf16<<<8192, 256, 0, stream>>>(key_in, kx, 2097152);
  cvt_f32_bf16<<<512, 256, 0, stream>>>(Wq_w, wq, 131072);
  cvt_f32_bf16<<<512, 256, 0, stream>>>(Wk_w, wk, 131072);
  transpose_v<<<dim3(32, 64, 8), dim3(32, 8), 0, stream>>>(value, vt);

  // projections: q = query @ Wq^T + b, k = key @ Wk^T + b   (bf16 out)
  gemm256<0, 0><<<dim3(4, 64, 1), 512, 0, stream>>>(
      qx, wq, qp, Wq_b, nullptr, 16384, 1024, 1024, 0, 0, 0);
  gemm256<0, 0><<<dim3(4, 64, 1), 512, 0, stream>>>(
      kx, wk, kp, Wk_b, nullptr, 16384, 1024, 1024, 0, 0, 0);
  // scores: S = mask ? (q @ k^T)/32 : -1e9   (bf16 out, batched)
  gemm256<1, 1><<<dim3(8, 8, 8), 512, 0, stream>>>(
      qp, kp, S, nullptr, mask, 2048, 2048, 1024, 2048LL * 1024,
      2048LL * 1024, 2048LL * 2048);
  softmax_rows<<<16384, 256, 0, stream>>>(S, P);
  // out = P @ V  (via V^T, f32 out, batched)
  gemm256<2, 1><<<dim3(4, 8, 8), 512, 0, stream>>>(
      P, vt, out, nullptr, nullptr, 2048, 1024, 2048, 2048LL * 2048,
      1024LL * 2048, 2048LL * 1024);
}